// Round 1
// baseline (523.943 us; speedup 1.0000x reference)
//
#include <hip/hip_runtime.h>

#define N_IMG 32
#define C_DIM 64
#define HW_SZ 4096
#define K_CODES 512
#define N_TOK (N_IMG * HW_SZ)   // 131072
#define TK 128

// ws layout (float offsets):
//   [0, 512)        cnt accumulator
//   [512, 33280)    avg accumulator [512][64]
//   [33280]         loss accumulator
//   [33536, 34048)  enorm[512]
//   [34048, ...)    idx[int, 131072]

__global__ void k_prep(const float* __restrict__ emb, float* __restrict__ enorm) {
    int k = blockIdx.x * blockDim.x + threadIdx.x;
    if (k < K_CODES) {
        const float* e = emb + k * 64;
        float d0 = 0.f, d1 = 0.f, d2 = 0.f, d3 = 0.f;
#pragma unroll
        for (int c = 0; c < 64; c += 4) {
            d0 = fmaf(e[c], e[c], d0);
            d1 = fmaf(e[c + 1], e[c + 1], d1);
            d2 = fmaf(e[c + 2], e[c + 2], d2);
            d3 = fmaf(e[c + 3], e[c + 3], d3);
        }
        enorm[k] = (d0 + d1) + (d2 + d3);
    }
}

__global__ __launch_bounds__(256) void k_main(const float* __restrict__ x,
                                              const float* __restrict__ emb,
                                              const float* __restrict__ enorm,
                                              float* __restrict__ qout,
                                              int* __restrict__ idx_out,
                                              float* __restrict__ loss_acc) {
    __shared__ float se[TK * 64];
    __shared__ float sen[TK];
    __shared__ float red[4];

    int t = blockIdx.x * 256 + threadIdx.x;
    int n = t >> 12;
    int hw = t & 4095;
    const float* xp = x + ((size_t)n * C_DIM) * HW_SZ + hw;

    float xv[64];
#pragma unroll
    for (int c = 0; c < 64; ++c) xv[c] = xp[(size_t)c * HW_SZ];

    float sxx;
    {
        float d0 = 0.f, d1 = 0.f, d2 = 0.f, d3 = 0.f;
#pragma unroll
        for (int c = 0; c < 64; c += 4) {
            d0 = fmaf(xv[c], xv[c], d0);
            d1 = fmaf(xv[c + 1], xv[c + 1], d1);
            d2 = fmaf(xv[c + 2], xv[c + 2], d2);
            d3 = fmaf(xv[c + 3], xv[c + 3], d3);
        }
        sxx = (d0 + d1) + (d2 + d3);
    }

    float best = 3.402823466e38f;
    int bestk = 0;

    for (int kt = 0; kt < K_CODES; kt += TK) {
        __syncthreads();
        // stage TK codes (TK*64 floats = TK*16 float4) into LDS, coalesced
        const float4* src = (const float4*)(emb + kt * 64);
        float4* dst = (float4*)se;
        for (int i = threadIdx.x; i < TK * 16; i += 256) dst[i] = src[i];
        if (threadIdx.x < TK) sen[threadIdx.x] = enorm[kt + threadIdx.x];
        __syncthreads();

        for (int kk = 0; kk < TK; ++kk) {
            const float* ep = se + kk * 64;
            float d0 = 0.f, d1 = 0.f, d2 = 0.f, d3 = 0.f;
#pragma unroll
            for (int c = 0; c < 64; c += 4) {
                d0 = fmaf(xv[c], ep[c], d0);
                d1 = fmaf(xv[c + 1], ep[c + 1], d1);
                d2 = fmaf(xv[c + 2], ep[c + 2], d2);
                d3 = fmaf(xv[c + 3], ep[c + 3], d3);
            }
            float dot = (d0 + d1) + (d2 + d3);
            float s = (sxx + sen[kk]) - 2.0f * dot;
            if (s < best) { best = s; bestk = kt + kk; }
        }
    }

    idx_out[t] = bestk;

    // epilogue: write quantized (NCHW) + loss partial
    const float* e = emb + bestk * 64;
    float* qp = qout + ((size_t)n * C_DIM) * HW_SZ + hw;
    float l0 = 0.f, l1 = 0.f, l2 = 0.f, l3 = 0.f;
#pragma unroll
    for (int c = 0; c < 64; c += 4) {
        float e0 = e[c], e1 = e[c + 1], e2 = e[c + 2], e3 = e[c + 3];
        qp[(size_t)c * HW_SZ] = e0;
        qp[(size_t)(c + 1) * HW_SZ] = e1;
        qp[(size_t)(c + 2) * HW_SZ] = e2;
        qp[(size_t)(c + 3) * HW_SZ] = e3;
        float f0 = xv[c] - e0, f1 = xv[c + 1] - e1, f2 = xv[c + 2] - e2, f3 = xv[c + 3] - e3;
        l0 = fmaf(f0, f0, l0);
        l1 = fmaf(f1, f1, l1);
        l2 = fmaf(f2, f2, l2);
        l3 = fmaf(f3, f3, l3);
    }
    float lp = (l0 + l1) + (l2 + l3);
#pragma unroll
    for (int off = 32; off; off >>= 1) lp += __shfl_down(lp, off);
    if ((threadIdx.x & 63) == 0) red[threadIdx.x >> 6] = lp;
    __syncthreads();
    if (threadIdx.x == 0) {
        float s = (red[0] + red[1]) + (red[2] + red[3]);
        atomicAdd(loss_acc, s);
    }
}

// one block per image n; LDS-resident [512][65] accumulator + counts, flush via global atomics
__global__ __launch_bounds__(1024) void k_seg(const float* __restrict__ x,
                                              const int* __restrict__ idx,
                                              float* __restrict__ cnt_g,
                                              float* __restrict__ avg_g) {
    __shared__ float acc[K_CODES * 65];
    __shared__ float cnt[K_CODES];
    int tid = threadIdx.x;
    for (int i = tid; i < K_CODES * 65; i += 1024) acc[i] = 0.f;
    for (int i = tid; i < K_CODES; i += 1024) cnt[i] = 0.f;
    __syncthreads();

    int n = blockIdx.x;
    const float* xp = x + (size_t)n * C_DIM * HW_SZ;
    const int* ip = idx + n * HW_SZ;

#pragma unroll
    for (int p = 0; p < 4; ++p) {
        int hw = p * 1024 + tid;
        int k = ip[hw];
        atomicAdd(&cnt[k], 1.0f);
        float* row = acc + k * 65;
#pragma unroll
        for (int c = 0; c < 64; ++c) {
            atomicAdd(&row[c], xp[(size_t)c * HW_SZ + hw]);
        }
    }
    __syncthreads();

    for (int i = tid; i < K_CODES * 64; i += 1024) {
        int k = i >> 6, c = i & 63;
        atomicAdd(&avg_g[i], acc[k * 65 + c]);
    }
    for (int i = tid; i < K_CODES; i += 1024) atomicAdd(&cnt_g[i], cnt[i]);
}

__global__ void k_fin(const float* __restrict__ cs_in, const float* __restrict__ avg_in,
                      const float* __restrict__ cnt, const float* __restrict__ avgacc,
                      const float* __restrict__ loss_acc,
                      float* __restrict__ loss_out, float* __restrict__ emb_out,
                      float* __restrict__ cs_out, float* __restrict__ avg_out) {
    int i = blockIdx.x * 256 + threadIdx.x;
    if (i >= K_CODES * 64) return;
    int k = i >> 6, c = i & 63;
    float ncs = cs_in[k] * 0.99f + 0.01f * cnt[k];
    float nav = avg_in[i] * 0.99f + 0.01f * avgacc[i];
    avg_out[i] = nav;
    emb_out[i] = nav / (ncs + 1e-5f);
    if (c == 0) cs_out[k] = ncs;
    if (i == 0) loss_out[0] = loss_acc[0] * (1.0f / 8388608.0f);
}

extern "C" void kernel_launch(void* const* d_in, const int* in_sizes, int n_in,
                              void* d_out, int out_size, void* d_ws, size_t ws_size,
                              hipStream_t stream) {
    (void)in_sizes; (void)n_in; (void)out_size; (void)ws_size;
    const float* x   = (const float*)d_in[0];
    const float* emb = (const float*)d_in[1];
    const float* cs  = (const float*)d_in[2];
    const float* avg = (const float*)d_in[3];

    float* out      = (float*)d_out;
    float* qout     = out;
    float* loss_out = out + 8388608;
    float* emb_out  = loss_out + 1;
    float* cs_out   = emb_out + 32768;
    float* avg_out  = cs_out + 512;

    float* wsf      = (float*)d_ws;
    float* cnt_acc  = wsf;
    float* avg_acc  = wsf + 512;
    float* loss_acc = wsf + 33280;
    float* enorm    = wsf + 33536;
    int*   idx      = (int*)(wsf + 34048);

    hipMemsetAsync(d_ws, 0, 33281 * sizeof(float), stream);
    k_prep<<<2, 256, 0, stream>>>(emb, enorm);
    k_main<<<N_TOK / 256, 256, 0, stream>>>(x, emb, enorm, qout, idx, loss_acc);
    k_seg<<<N_IMG, 1024, 0, stream>>>(x, idx, cnt_acc, avg_acc);
    k_fin<<<128, 256, 0, stream>>>(cs, avg, cnt_acc, avg_acc, loss_acc,
                                   loss_out, emb_out, cs_out, avg_out);
}

// Round 2
// 219.574 us; speedup vs baseline: 2.3862x; 2.3862x over previous
//
#include <hip/hip_runtime.h>

#define N_IMG 32
#define C_DIM 64
#define HW_SZ 4096
#define K_CODES 512
#define N_TOK (N_IMG * HW_SZ)   // 131072
#define TK 128

// ws layout (float offsets):
//   [0, 512)        cnt accumulator
//   [512, 33280)    avg accumulator [512][64]
//   [33280]         loss accumulator
//   [33536, 34048)  enorm[512]
//   [34048, ...)    idx[int, 131072]

__global__ void k_prep(const float* __restrict__ emb, float* __restrict__ enorm) {
    int k = blockIdx.x * blockDim.x + threadIdx.x;
    if (k < K_CODES) {
        const float* e = emb + k * 64;
        float d0 = 0.f, d1 = 0.f, d2 = 0.f, d3 = 0.f;
#pragma unroll
        for (int c = 0; c < 64; c += 4) {
            d0 = fmaf(e[c], e[c], d0);
            d1 = fmaf(e[c + 1], e[c + 1], d1);
            d2 = fmaf(e[c + 2], e[c + 2], d2);
            d3 = fmaf(e[c + 3], e[c + 3], d3);
        }
        enorm[k] = (d0 + d1) + (d2 + d3);
    }
}

// 2 tokens per thread: each staged LDS e-value feeds 2 FMA streams -> FMA-bound.
__global__ __launch_bounds__(256) void k_main(const float* __restrict__ x,
                                              const float* __restrict__ emb,
                                              const float* __restrict__ enorm,
                                              float* __restrict__ qout,
                                              int* __restrict__ idx_out,
                                              float* __restrict__ loss_acc) {
    __shared__ float se[TK * 64];
    __shared__ float sen[TK];
    __shared__ float red[4];

    int tid = threadIdx.x;
    int base = blockIdx.x * 512;          // 512 tokens per block, same image
    int n = base >> 12;
    int hw0 = (base & 4095) + tid;
    int hw1 = hw0 + 256;
    const float* xp = x + (size_t)n * C_DIM * HW_SZ;

    float xa[64], xb[64];
#pragma unroll
    for (int c = 0; c < 64; ++c) {
        xa[c] = xp[(size_t)c * HW_SZ + hw0];
        xb[c] = xp[(size_t)c * HW_SZ + hw1];
    }

    float sxxa, sxxb;
    {
        float a0 = 0.f, a1 = 0.f, a2 = 0.f, a3 = 0.f;
        float b0 = 0.f, b1 = 0.f, b2 = 0.f, b3 = 0.f;
#pragma unroll
        for (int c = 0; c < 64; c += 4) {
            a0 = fmaf(xa[c], xa[c], a0);     b0 = fmaf(xb[c], xb[c], b0);
            a1 = fmaf(xa[c + 1], xa[c + 1], a1); b1 = fmaf(xb[c + 1], xb[c + 1], b1);
            a2 = fmaf(xa[c + 2], xa[c + 2], a2); b2 = fmaf(xb[c + 2], xb[c + 2], b2);
            a3 = fmaf(xa[c + 3], xa[c + 3], a3); b3 = fmaf(xb[c + 3], xb[c + 3], b3);
        }
        sxxa = (a0 + a1) + (a2 + a3);
        sxxb = (b0 + b1) + (b2 + b3);
    }

    float besta = 3.402823466e38f, bestb = 3.402823466e38f;
    int ka = 0, kb = 0;

    for (int kt = 0; kt < K_CODES; kt += TK) {
        __syncthreads();
        const float4* src = (const float4*)(emb + kt * 64);
        float4* dst = (float4*)se;
        for (int i = tid; i < TK * 16; i += 256) dst[i] = src[i];
        if (tid < TK) sen[tid] = enorm[kt + tid];
        __syncthreads();

        for (int kk = 0; kk < TK; ++kk) {
            const float* ep = se + kk * 64;
            float a0 = 0.f, a1 = 0.f, a2 = 0.f, a3 = 0.f;
            float b0 = 0.f, b1 = 0.f, b2 = 0.f, b3 = 0.f;
#pragma unroll
            for (int c = 0; c < 64; c += 4) {
                float e0 = ep[c], e1 = ep[c + 1], e2 = ep[c + 2], e3 = ep[c + 3];
                a0 = fmaf(xa[c], e0, a0);     b0 = fmaf(xb[c], e0, b0);
                a1 = fmaf(xa[c + 1], e1, a1); b1 = fmaf(xb[c + 1], e1, b1);
                a2 = fmaf(xa[c + 2], e2, a2); b2 = fmaf(xb[c + 2], e2, b2);
                a3 = fmaf(xa[c + 3], e3, a3); b3 = fmaf(xb[c + 3], e3, b3);
            }
            float dota = (a0 + a1) + (a2 + a3);
            float dotb = (b0 + b1) + (b2 + b3);
            float en = sen[kk];
            float sa = (sxxa + en) - 2.0f * dota;
            float sb = (sxxb + en) - 2.0f * dotb;
            if (sa < besta) { besta = sa; ka = kt + kk; }
            if (sb < bestb) { bestb = sb; kb = kt + kk; }
        }
    }

    idx_out[base + tid] = ka;
    idx_out[base + 256 + tid] = kb;

    const float* ea = emb + ka * 64;
    const float* eb = emb + kb * 64;
    float* qp = qout + (size_t)n * C_DIM * HW_SZ;
    float l0 = 0.f, l1 = 0.f;
#pragma unroll
    for (int c = 0; c < 64; ++c) {
        float va = ea[c], vb = eb[c];
        qp[(size_t)c * HW_SZ + hw0] = va;
        qp[(size_t)c * HW_SZ + hw1] = vb;
        float fa = xa[c] - va, fb = xb[c] - vb;
        l0 = fmaf(fa, fa, l0);
        l1 = fmaf(fb, fb, l1);
    }
    float lp = l0 + l1;
#pragma unroll
    for (int off = 32; off; off >>= 1) lp += __shfl_down(lp, off);
    if ((tid & 63) == 0) red[tid >> 6] = lp;
    __syncthreads();
    if (tid == 0) {
        float s = (red[0] + red[1]) + (red[2] + red[3]);
        atomicAdd(loss_acc, s);
    }
}

// grid = (32 images) x (8 channel-groups) = 256 blocks, 1024 threads.
// LDS acc [512][9] (pad 9: coprime to 32 banks -> random-k atomics spread).
__global__ __launch_bounds__(1024) void k_seg(const float* __restrict__ x,
                                              const int* __restrict__ idx,
                                              float* __restrict__ cnt_g,
                                              float* __restrict__ avg_g) {
    __shared__ float acc[K_CODES * 9];
    __shared__ float cnt[K_CODES];
    int tid = threadIdx.x;
    int n = blockIdx.x >> 3;
    int cg = blockIdx.x & 7;

    for (int i = tid; i < K_CODES * 9; i += 1024) acc[i] = 0.f;
    if (cg == 0 && tid < K_CODES) cnt[tid] = 0.f;
    __syncthreads();

    const float* xp = x + (size_t)n * C_DIM * HW_SZ + (size_t)(cg * 8) * HW_SZ;
    const int* ip = idx + n * HW_SZ;

#pragma unroll
    for (int p = 0; p < 4; ++p) {
        int hw = p * 1024 + tid;
        int k = ip[hw];
        if (cg == 0) atomicAdd(&cnt[k], 1.0f);
        float* row = acc + k * 9;
#pragma unroll
        for (int j = 0; j < 8; ++j) {
            atomicAdd(&row[j], xp[(size_t)j * HW_SZ + hw]);
        }
    }
    __syncthreads();

    for (int i = tid; i < K_CODES * 8; i += 1024) {
        int k = i >> 3, j = i & 7;
        atomicAdd(&avg_g[k * 64 + cg * 8 + j], acc[k * 9 + j]);
    }
    if (cg == 0 && tid < K_CODES) atomicAdd(&cnt_g[tid], cnt[tid]);
}

__global__ void k_fin(const float* __restrict__ cs_in, const float* __restrict__ avg_in,
                      const float* __restrict__ cnt, const float* __restrict__ avgacc,
                      const float* __restrict__ loss_acc,
                      float* __restrict__ loss_out, float* __restrict__ emb_out,
                      float* __restrict__ cs_out, float* __restrict__ avg_out) {
    int i = blockIdx.x * 256 + threadIdx.x;
    if (i >= K_CODES * 64) return;
    int k = i >> 6, c = i & 63;
    float ncs = cs_in[k] * 0.99f + 0.01f * cnt[k];
    float nav = avg_in[i] * 0.99f + 0.01f * avgacc[i];
    avg_out[i] = nav;
    emb_out[i] = nav / (ncs + 1e-5f);
    if (c == 0) cs_out[k] = ncs;
    if (i == 0) loss_out[0] = loss_acc[0] * (1.0f / 8388608.0f);
}

extern "C" void kernel_launch(void* const* d_in, const int* in_sizes, int n_in,
                              void* d_out, int out_size, void* d_ws, size_t ws_size,
                              hipStream_t stream) {
    (void)in_sizes; (void)n_in; (void)out_size; (void)ws_size;
    const float* x   = (const float*)d_in[0];
    const float* emb = (const float*)d_in[1];
    const float* cs  = (const float*)d_in[2];
    const float* avg = (const float*)d_in[3];

    float* out      = (float*)d_out;
    float* qout     = out;
    float* loss_out = out + 8388608;
    float* emb_out  = loss_out + 1;
    float* cs_out   = emb_out + 32768;
    float* avg_out  = cs_out + 512;

    float* wsf      = (float*)d_ws;
    float* cnt_acc  = wsf;
    float* avg_acc  = wsf + 512;
    float* loss_acc = wsf + 33280;
    float* enorm    = wsf + 33536;
    int*   idx      = (int*)(wsf + 34048);

    hipMemsetAsync(d_ws, 0, 33281 * sizeof(float), stream);
    k_prep<<<2, 256, 0, stream>>>(emb, enorm);
    k_main<<<N_TOK / 512, 256, 0, stream>>>(x, emb, enorm, qout, idx, loss_acc);
    k_seg<<<256, 1024, 0, stream>>>(x, idx, cnt_acc, avg_acc);
    k_fin<<<128, 256, 0, stream>>>(cs, avg, cnt_acc, avg_acc, loss_acc,
                                   loss_out, emb_out, cs_out, avg_out);
}